// Round 5
// baseline (156.894 us; speedup 1.0000x reference)
//
#include <hip/hip_runtime.h>

#define N_NODES 100000
#define N_EDGES 640000
#define F 128
#define NT 6250          // 16-node tiles (100000 = 6250*16 exactly)
#define NBLK 512         // node_proj blocks; tiles stride NBLK
#define EBLK 2500        // edge_score blocks (256 edges each)

typedef __attribute__((ext_vector_type(8))) short short8;
typedef __attribute__((ext_vector_type(4))) float float4v;

// RNE float -> bf16 bits
static __device__ __forceinline__ unsigned short f2bf(float f) {
    unsigned int u = __float_as_uint(f);
    u += 0x7fffu + ((u >> 16) & 1u);
    return (unsigned short)(u >> 16);
}

// ---------------------------------------------------------------------------
// Kernel 1: node projections — r2 structure (best measured) + INTEGRATED
// W1 transform (prep_wt kernel eliminated; 3 dispatches -> 2).
// Each block builds its own swizzled W LDS image directly from W1:
//   8 slabs of 32 W1 rows; per slab: coalesced float4 reads -> bf16 scratch
//   (scratch overlaps oA/oB bytes, consumed before their first use) ->
//   conflict-free u16 column reads -> w_swz chunks (identical image to the
//   old prep_wt + staging path; MFMA inputs bit-identical).
// Main loop unchanged: fused A+B, 2 blocks/CU, depth-2 register prefetch,
// LDS-staged contiguous epilogue.
// LDS: 64 (w_swz) + 4.25 (hb) + 2x4.25 (oA,oB) = 76.75 KB -> 2 blocks/CU.
// ---------------------------------------------------------------------------
__global__ __launch_bounds__(256, 2) void node_proj(
    const float* __restrict__ h, const float* __restrict__ W1,
    const float* __restrict__ b1,
    unsigned short* __restrict__ A, unsigned short* __restrict__ B)
{
    __shared__ __align__(16) unsigned char pool[65536 + 3 * 16 * 136 * 2];
    unsigned short* w_swz = (unsigned short*)pool;            // [256*128] swizzled
    unsigned short* hb = (unsigned short*)(pool + 65536);     // [16*136]
    unsigned short* oA = hb + 16 * 136;                       // [16*136]
    unsigned short* oB = oA + 16 * 136;                       // [16*136]

    const int tid  = threadIdx.x;
    const int lane = tid & 63;
    const int l16  = lane & 15;
    const int quad = lane >> 4;
    const int w    = tid >> 6;            // wave id 0..3

    // ---- integrated W1 -> w_swz transform (replaces prep_wt dispatch) ----
    // w_swz chunk (r,c) at slot r*16 + (c^(r&15)), chunk = Wt[r][c*8..c*8+8],
    // Wt[n][k] = bf16(W1[(n&128)+k][n&127]).
    {
        unsigned short* scratch = oA;     // 8448B, overlaps oA+oB (consumed
                                          // before their first write below)
        for (int s = 0; s < 8; ++s) {
            // stage slab s = W1 rows [s*32, s*32+32) as bf16 [32][132]
#pragma unroll
            for (int q = 0; q < 4; ++q) {
                int f = q * 256 + tid;            // float4 idx 0..1023
                int rsl = f >> 5, c4 = f & 31;
                float4 v = *(const float4*)(W1 + (size_t)(s * 32 + rsl) * 128 + c4 * 4);
                uint2 p;
                p.x = (unsigned)f2bf(v.x) | ((unsigned)f2bf(v.y) << 16);
                p.y = (unsigned)f2bf(v.z) | ((unsigned)f2bf(v.w) << 16);
                *(uint2*)&scratch[rsl * 132 + c4 * 4] = p;
            }
            __syncthreads();
            // assemble chunks: slab covers Wt cols k in [(s&3)*32,+32),
            // n-half: s<4 -> n=nn (A rows), s>=4 -> n=128+nn (B rows)
#pragma unroll
            for (int j = 0; j < 2; ++j) {
                int cl = j * 256 + tid;           // 0..511
                int c_rel = cl >> 7, nn = cl & 127;
                int n = (s < 4 ? 0 : 128) + nn;
                int c = (s & 3) * 4 + c_rel;
                union { unsigned short u[8]; uint4 v; } ck;
#pragma unroll
                for (int e = 0; e < 8; ++e)
                    ck.u[e] = scratch[(c_rel * 8 + e) * 132 + nn];  // 2 lanes/bank: free
                *(uint4*)&w_swz[((n << 4) + (c ^ (n & 15))) * 8] = ck.v;
            }
            __syncthreads();
        }
    }

    // bias frags: waves 0,1 own A cols (w&1)*64 + p*16 + quad*4
    const bool isA = (w < 2);
    const int colb = (w & 1) * 64;
    float4 bv[4];
#pragma unroll
    for (int p = 0; p < 4; ++p) {
        int col = colb + p * 16 + quad * 4;
        bv[p] = isA ? *(const float4*)(b1 + col) : make_float4(0.f, 0.f, 0.f, 0.f);
    }
    unsigned short* ostage = isA ? oA : oB;

    // staging coords: float4 f = i*256+tid, i<2; row=f>>5 (0..15), c4=f&31
    int srow[2], sc4[2];
#pragma unroll
    for (int i = 0; i < 2; ++i) { int f = i * 256 + tid; srow[i] = f >> 5; sc4[i] = f & 31; }

#define LOADH(PF, T)                                                           \
    _Pragma("unroll") for (int i = 0; i < 2; ++i)                              \
        PF[i] = *(const float4*)(h + ((size_t)(T) * 16 + srow[i]) * F + sc4[i] * 4);

#define CVTWRITE(PF)                                                           \
    _Pragma("unroll") for (int i = 0; i < 2; ++i) {                            \
        uint2 p;                                                               \
        p.x = (unsigned)f2bf(PF[i].x) | ((unsigned)f2bf(PF[i].y) << 16);       \
        p.y = (unsigned)f2bf(PF[i].z) | ((unsigned)f2bf(PF[i].w) << 16);       \
        *(uint2*)&hb[srow[i] * 136 + sc4[i] * 4] = p;                          \
    }

    int t = blockIdx.x;                   // 512 < 6250: tile 0 always valid
    float4 pfA[2], pfB[2];
    LOADH(pfA, t); CVTWRITE(pfA);         // tile t -> hb
    LOADH(pfA, t + NBLK);                 // depth-1 prefill (bid+512 < 6250 always)
    __syncthreads();                      // w_swz + tile t staged

    while (t < NT) {
        const int tn  = t + NBLK;
        const int tnn = tn + NBLK;
        if (tnn < NT) LOADH(pfB, tnn);    // depth-2 prefetch: consumed NEXT iter

        // ---- MFMA tile t: wave w -> wcols w*64 .. w*64+63 ----
        float4v acc[4];
#pragma unroll
        for (int p = 0; p < 4; ++p) acc[p] = (float4v){0.f, 0.f, 0.f, 0.f};
#pragma unroll
        for (int k0 = 0; k0 < 4; ++k0) {
            short8 bf = *(const short8*)&hb[l16 * 136 + k0 * 32 + quad * 8];
            const int cc = (k0 * 4 + quad);
#pragma unroll
            for (int p = 0; p < 4; ++p) {
                const int row = w * 64 + p * 16 + l16;     // row & 15 == l16
                short8 af = *(const short8*)&w_swz[((row << 4) + (cc ^ l16)) * 8];
                acc[p] = __builtin_amdgcn_mfma_f32_16x16x32_bf16(af, bf, acc[p], 0, 0, 0);
            }
        }
        __syncthreads();                  // B1: hb(t) + oX(t-1) reads done

        if (tn < NT) CVTWRITE(pfA);       // tile t+1 into hb (loaded 1 iter ago)
        // stage acc -> out LDS (node=l16 row, bias folded here)
#pragma unroll
        for (int p = 0; p < 4; ++p) {
            ushort4 sv;
            sv.x = f2bf(acc[p][0] + bv[p].x);
            sv.y = f2bf(acc[p][1] + bv[p].y);
            sv.z = f2bf(acc[p][2] + bv[p].z);
            sv.w = f2bf(acc[p][3] + bv[p].w);
            *(ushort4*)&ostage[l16 * 136 + colb + p * 16 + quad * 4] = sv;
        }
        __syncthreads();                  // B2: hb(t+1) + oX(t) written

        // ---- contiguous stores: thread tid -> row tid>>4, chunk tid&15 ----
        {
            const int r = tid >> 4, c = tid & 15;
            const size_t goff = ((size_t)t * 16 + r) * F + c * 8;
            *(uint4*)(A + goff) = *(const uint4*)&oA[r * 136 + c * 8];
            *(uint4*)(B + goff) = *(const uint4*)&oB[r * 136 + c * 8];
        }

        // rotate prefetch registers
#pragma unroll
        for (int i = 0; i < 2; ++i) pfA[i] = pfB[i];
        t = tn;
    }
#undef LOADH
#undef CVTWRITE
}

// ---------------------------------------------------------------------------
// Kernel 2: per-edge score (r4 version, unchanged). 256 edges/block, two
// batches of 4 edges/thread, all 32 row-gathers issued up front.
// r4 established this phase is fabric/service-rate-bound (~3.4 TB/s beyond
// L2), not concurrency-bound.
// ---------------------------------------------------------------------------
__global__ __launch_bounds__(256) void edge_score(
    const unsigned short* __restrict__ A, const unsigned short* __restrict__ B,
    const int* __restrict__ src, const int* __restrict__ dst,
    const float* __restrict__ W2, const float* __restrict__ b2,
    float* __restrict__ out)
{
    const int tid = threadIdx.x;
    const int sub = tid & 7;
    const int e0  = blockIdx.x * 256 + (tid >> 3) * 4;   // batch 0
    const int e1  = e0 + 128;                            // batch 1

    const int4 sv0 = *(const int4*)(src + e0);
    const int4 dv0 = *(const int4*)(dst + e0);
    const int4 sv1 = *(const int4*)(src + e1);
    const int4 dv1 = *(const int4*)(dst + e1);
    const int s0[4] = {sv0.x, sv0.y, sv0.z, sv0.w};
    const int d0[4] = {dv0.x, dv0.y, dv0.z, dv0.w};
    const int s1[4] = {sv1.x, sv1.y, sv1.z, sv1.w};
    const int d1[4] = {dv1.x, dv1.y, dv1.z, dv1.w};

    uint4 a00[4], a01[4], b00[4], b01[4];   // batch 0
    uint4 a10[4], a11[4], b10[4], b11[4];   // batch 1
#pragma unroll
    for (int i = 0; i < 4; ++i) {
        const unsigned short* Ar = A + (size_t)s0[i] * F;
        const unsigned short* Br = B + (size_t)d0[i] * F;
        a00[i] = *(const uint4*)(Ar + sub * 8);
        a01[i] = *(const uint4*)(Ar + 64 + sub * 8);
        b00[i] = *(const uint4*)(Br + sub * 8);
        b01[i] = *(const uint4*)(Br + 64 + sub * 8);
    }
#pragma unroll
    for (int i = 0; i < 4; ++i) {
        const unsigned short* Ar = A + (size_t)s1[i] * F;
        const unsigned short* Br = B + (size_t)d1[i] * F;
        a10[i] = *(const uint4*)(Ar + sub * 8);
        a11[i] = *(const uint4*)(Ar + 64 + sub * 8);
        b10[i] = *(const uint4*)(Br + sub * 8);
        b11[i] = *(const uint4*)(Br + 64 + sub * 8);
    }

    const float4 w0 = *(const float4*)(W2 + sub * 8);
    const float4 w1 = *(const float4*)(W2 + sub * 8 + 4);
    const float4 w2 = *(const float4*)(W2 + 64 + sub * 8);
    const float4 w3 = *(const float4*)(W2 + 64 + sub * 8 + 4);
    const float bias = b2[0];

#define TERM(UA, UB, WL, WH)                                                   \
    {                                                                          \
        float fa0 = __uint_as_float((UA) << 16);                               \
        float fa1 = __uint_as_float((UA) & 0xFFFF0000u);                       \
        float fb0 = __uint_as_float((UB) << 16);                               \
        float fb1 = __uint_as_float((UB) & 0xFFFF0000u);                       \
        sacc = fmaf(fmaxf(fa0 + fb0, 0.f), (WL), sacc);                        \
        sacc = fmaf(fmaxf(fa1 + fb1, 0.f), (WH), sacc);                        \
    }
#define BATCH(AV0, AV1, BV0, BV1, EBASE)                                       \
    _Pragma("unroll")                                                          \
    for (int i = 0; i < 4; ++i) {                                              \
        float sacc = 0.f;                                                      \
        TERM(AV0[i].x, BV0[i].x, w0.x, w0.y)                                   \
        TERM(AV0[i].y, BV0[i].y, w0.z, w0.w)                                   \
        TERM(AV0[i].z, BV0[i].z, w1.x, w1.y)                                   \
        TERM(AV0[i].w, BV0[i].w, w1.z, w1.w)                                   \
        TERM(AV1[i].x, BV1[i].x, w2.x, w2.y)                                   \
        TERM(AV1[i].y, BV1[i].y, w2.z, w2.w)                                   \
        TERM(AV1[i].z, BV1[i].z, w3.x, w3.y)                                   \
        TERM(AV1[i].w, BV1[i].w, w3.z, w3.w)                                   \
        sacc += __shfl_xor(sacc, 1);                                           \
        sacc += __shfl_xor(sacc, 2);                                           \
        sacc += __shfl_xor(sacc, 4);                                           \
        if (sub == 0) out[(EBASE) + i] = sacc + bias;                          \
    }

    BATCH(a00, a01, b00, b01, e0)
    BATCH(a10, a11, b10, b11, e1)
#undef BATCH
#undef TERM
}

extern "C" void kernel_launch(void* const* d_in, const int* in_sizes, int n_in,
                              void* d_out, int out_size, void* d_ws, size_t ws_size,
                              hipStream_t stream) {
    const float* h   = (const float*)d_in[0];
    const int*   src = (const int*)d_in[1];
    const int*   dst = (const int*)d_in[2];
    const float* W1  = (const float*)d_in[3];
    const float* b1  = (const float*)d_in[4];
    const float* W2  = (const float*)d_in[5];
    const float* b2  = (const float*)d_in[6];
    float* out = (float*)d_out;

    // workspace layout (bf16): A[100000][128] | B[100000][128]
    unsigned short* A = (unsigned short*)d_ws;
    unsigned short* B = A + (size_t)N_NODES * F;

    node_proj<<<NBLK, 256, 0, stream>>>(h, W1, b1, A, B);
    edge_score<<<EBLK, 256, 0, stream>>>(A, B, src, dst, W2, b2, out);
}

// Round 6
// 139.593 us; speedup vs baseline: 1.1239x; 1.1239x over previous
//
#include <hip/hip_runtime.h>

#define N_NODES 100000
#define N_EDGES 640000
#define F 128
#define NT 6250          // 16-node tiles (100000 = 6250*16 exactly)
#define NBLK 512         // node_proj blocks; tiles stride NBLK
#define EBLK 2500        // edge_score blocks (256 edges each)

typedef __attribute__((ext_vector_type(8))) short short8;
typedef __attribute__((ext_vector_type(4))) float float4v;

// RNE float -> bf16 bits
static __device__ __forceinline__ unsigned short f2bf(float f) {
    unsigned int u = __float_as_uint(f);
    u += 0x7fffu + ((u >> 16) & 1u);
    return (unsigned short)(u >> 16);
}

// ---------------------------------------------------------------------------
// Kernel 0: transpose+convert W1 (fp32 [256][128]) into Wt bf16 [256][128]:
//   Wt[n][k] = W1[(n&128)+k][n&127]
// ---------------------------------------------------------------------------
__global__ __launch_bounds__(256) void prep_wt(
    const float* __restrict__ W1, unsigned short* __restrict__ Wt)
{
    int id = blockIdx.x * 256 + threadIdx.x;       // 0 .. 32767
    int n = id >> 7, k = id & 127;
    float v = W1[((n & 128) + k) * 128 + (n & 127)];
    Wt[id] = f2bf(v);
}

// ---------------------------------------------------------------------------
// Kernel 1: node projections — r2 main loop (best measured) + INT8 OUTPUT.
// After the LDS out-stage (oA/oB assembled per 16-node tile), compute the
// per-row absmax (4x shfl_xor within the row's 16 lanes), quantize the row
// to int8 (q = rint(v * 127/max)), store 128 B/row + fp32 scale per row.
// Halves node_proj write traffic AND edge_score's gathered bytes.
// LDS: 64 (w_swz) + 4.25 (hb) + 2x4.25 (oA,oB) = 76.75 KB -> 2 blocks/CU.
// ---------------------------------------------------------------------------
__global__ __launch_bounds__(256, 2) void node_proj(
    const float* __restrict__ h, const unsigned short* __restrict__ Wt,
    const float* __restrict__ b1,
    unsigned char* __restrict__ A8, unsigned char* __restrict__ B8,
    float* __restrict__ sA, float* __restrict__ sB)
{
    __shared__ unsigned short w_swz[256 * 128];   // 64 KB, swizzled chunks
    __shared__ unsigned short hb[16 * 136];       // h tile (padded rows)
    __shared__ unsigned short oA[16 * 136];       // A out-stage (bf16)
    __shared__ unsigned short oB[16 * 136];       // B out-stage (bf16)

    const int tid  = threadIdx.x;
    const int lane = tid & 63;
    const int l16  = lane & 15;
    const int quad = lane >> 4;
    const int w    = tid >> 6;            // wave id 0..3

    // ---- stage full Wt into swizzled LDS (coalesced global reads) ----
#pragma unroll
    for (int i = 0; i < 16; ++i) {
        int cl = i * 256 + tid;           // chunk id 0..4095
        int r = cl >> 4, c = cl & 15;
        uint4 v = *(const uint4*)(Wt + (size_t)r * F + c * 8);
        *(uint4*)&w_swz[((r << 4) + (c ^ (r & 15))) * 8] = v;
    }

    // bias frags: waves 0,1 own A cols (w&1)*64 + p*16 + quad*4
    const bool isA = (w < 2);
    const int colb = (w & 1) * 64;
    float4 bv[4];
#pragma unroll
    for (int p = 0; p < 4; ++p) {
        int col = colb + p * 16 + quad * 4;
        bv[p] = isA ? *(const float4*)(b1 + col) : make_float4(0.f, 0.f, 0.f, 0.f);
    }
    unsigned short* ostage = isA ? oA : oB;

    // staging coords: float4 f = i*256+tid, i<2; row=f>>5 (0..15), c4=f&31
    int srow[2], sc4[2];
#pragma unroll
    for (int i = 0; i < 2; ++i) { int f = i * 256 + tid; srow[i] = f >> 5; sc4[i] = f & 31; }

#define LOADH(PF, T)                                                           \
    _Pragma("unroll") for (int i = 0; i < 2; ++i)                              \
        PF[i] = *(const float4*)(h + ((size_t)(T) * 16 + srow[i]) * F + sc4[i] * 4);

#define CVTWRITE(PF)                                                           \
    _Pragma("unroll") for (int i = 0; i < 2; ++i) {                            \
        uint2 p;                                                               \
        p.x = (unsigned)f2bf(PF[i].x) | ((unsigned)f2bf(PF[i].y) << 16);       \
        p.y = (unsigned)f2bf(PF[i].z) | ((unsigned)f2bf(PF[i].w) << 16);       \
        *(uint2*)&hb[srow[i] * 136 + sc4[i] * 4] = p;                          \
    }

    int t = blockIdx.x;                   // 512 < 6250: tile 0 always valid
    float4 pfA[2], pfB[2];
    LOADH(pfA, t); CVTWRITE(pfA);         // tile t -> hb
    LOADH(pfA, t + NBLK);                 // depth-1 prefill (bid+512 < 6250 always)
    __syncthreads();                      // Wt + tile t staged

    while (t < NT) {
        const int tn  = t + NBLK;
        const int tnn = tn + NBLK;
        if (tnn < NT) LOADH(pfB, tnn);    // depth-2 prefetch: consumed NEXT iter

        // ---- MFMA tile t: wave w -> wcols w*64 .. w*64+63 ----
        float4v acc[4];
#pragma unroll
        for (int p = 0; p < 4; ++p) acc[p] = (float4v){0.f, 0.f, 0.f, 0.f};
#pragma unroll
        for (int k0 = 0; k0 < 4; ++k0) {
            short8 bf = *(const short8*)&hb[l16 * 136 + k0 * 32 + quad * 8];
            const int cc = (k0 * 4 + quad);
#pragma unroll
            for (int p = 0; p < 4; ++p) {
                const int row = w * 64 + p * 16 + l16;     // row & 15 == l16
                short8 af = *(const short8*)&w_swz[((row << 4) + (cc ^ l16)) * 8];
                acc[p] = __builtin_amdgcn_mfma_f32_16x16x32_bf16(af, bf, acc[p], 0, 0, 0);
            }
        }
        __syncthreads();                  // B1: hb(t) + oX(t-1) reads done

        if (tn < NT) CVTWRITE(pfA);       // tile t+1 into hb (loaded 1 iter ago)
        // stage acc -> out LDS (node=l16 row, bias folded here)
#pragma unroll
        for (int p = 0; p < 4; ++p) {
            ushort4 sv;
            sv.x = f2bf(acc[p][0] + bv[p].x);
            sv.y = f2bf(acc[p][1] + bv[p].y);
            sv.z = f2bf(acc[p][2] + bv[p].z);
            sv.w = f2bf(acc[p][3] + bv[p].w);
            *(ushort4*)&ostage[l16 * 136 + colb + p * 16 + quad * 4] = sv;
        }
        __syncthreads();                  // B2: hb(t+1) + oX(t) written

        // ---- per-row int8 quantization + contiguous stores ----
        {
            const int r = tid >> 4, c = tid & 15;          // row 0..15, chunk 0..15
            const int node = t * 16 + r;
            uint4 va = *(const uint4*)&oA[r * 136 + c * 8];
            uint4 vb = *(const uint4*)&oB[r * 136 + c * 8];
            float fa[8], fb[8];
#define UNPK(W, F0, F1)                                                        \
            F0 = __uint_as_float((W) << 16);                                   \
            F1 = __uint_as_float((W) & 0xFFFF0000u);
            UNPK(va.x, fa[0], fa[1]) UNPK(va.y, fa[2], fa[3])
            UNPK(va.z, fa[4], fa[5]) UNPK(va.w, fa[6], fa[7])
            UNPK(vb.x, fb[0], fb[1]) UNPK(vb.y, fb[2], fb[3])
            UNPK(vb.z, fb[4], fb[5]) UNPK(vb.w, fb[6], fb[7])
#undef UNPK
            float ma = 0.f, mb = 0.f;
#pragma unroll
            for (int j = 0; j < 8; ++j) {
                ma = fmaxf(ma, fabsf(fa[j]));
                mb = fmaxf(mb, fabsf(fb[j]));
            }
            // row max across the 16 lanes of this row (contiguous in wave)
#pragma unroll
            for (int m = 1; m < 16; m <<= 1) {
                ma = fmaxf(ma, __shfl_xor(ma, m));
                mb = fmaxf(mb, __shfl_xor(mb, m));
            }
            const float inva = ma > 0.f ? 127.f / ma : 0.f;
            const float invb = mb > 0.f ? 127.f / mb : 0.f;
            uint2 qa, qb; qa.x = qa.y = qb.x = qb.y = 0u;
#pragma unroll
            for (int j = 0; j < 4; ++j) {
                qa.x |= ((unsigned)((int)rintf(fa[j] * inva) & 255)) << (8 * j);
                qa.y |= ((unsigned)((int)rintf(fa[j + 4] * inva) & 255)) << (8 * j);
                qb.x |= ((unsigned)((int)rintf(fb[j] * invb) & 255)) << (8 * j);
                qb.y |= ((unsigned)((int)rintf(fb[j + 4] * invb) & 255)) << (8 * j);
            }
            *(uint2*)(A8 + (size_t)node * 128 + c * 8) = qa;
            *(uint2*)(B8 + (size_t)node * 128 + c * 8) = qb;
            if (c == 0) {
                sA[node] = ma * (1.f / 127.f);
                sB[node] = mb * (1.f / 127.f);
            }
        }

        // rotate prefetch registers
#pragma unroll
        for (int i = 0; i < 2; ++i) pfA[i] = pfB[i];
        t = tn;
    }
#undef LOADH
#undef CVTWRITE
}

// ---------------------------------------------------------------------------
// Kernel 2: per-edge score over INT8 rows (128 B/row, halved fetch).
//   hidden_k = relu(qa_k*sa + qb_k*sb); score = sum hidden_k * w2_k + b2.
// Structure: r4's 256 edges/block, two batches of 4 edges/thread, all
// gathers issued up front. Lane sub covers channels [sub*8,+8) and
// [64+sub*8,+8) -> 8 lanes read 64 contiguous bytes per row-half.
// ---------------------------------------------------------------------------
static __device__ __forceinline__ float dot4q(
    unsigned ua, unsigned ub, float sa, float sb, float4 wv, float acc)
{
    const float* wp = &wv.x;
#pragma unroll
    for (int j = 0; j < 4; ++j) {
        float fa = (float)((int)(signed char)(ua >> (8 * j)));
        float fb = (float)((int)(signed char)(ub >> (8 * j)));
        float hv = fmaf(fa, sa, fb * sb);
        acc = fmaf(fmaxf(hv, 0.f), wp[j], acc);
    }
    return acc;
}

__global__ __launch_bounds__(256) void edge_score(
    const unsigned char* __restrict__ A8, const unsigned char* __restrict__ B8,
    const float* __restrict__ sA, const float* __restrict__ sB,
    const int* __restrict__ src, const int* __restrict__ dst,
    const float* __restrict__ W2, const float* __restrict__ b2,
    float* __restrict__ out)
{
    const int tid = threadIdx.x;
    const int sub = tid & 7;
    const int e0  = blockIdx.x * 256 + (tid >> 3) * 4;   // batch 0
    const int e1  = e0 + 128;                            // batch 1

    const int4 sv0 = *(const int4*)(src + e0);
    const int4 dv0 = *(const int4*)(dst + e0);
    const int4 sv1 = *(const int4*)(src + e1);
    const int4 dv1 = *(const int4*)(dst + e1);
    const int s0[4] = {sv0.x, sv0.y, sv0.z, sv0.w};
    const int d0[4] = {dv0.x, dv0.y, dv0.z, dv0.w};
    const int s1[4] = {sv1.x, sv1.y, sv1.z, sv1.w};
    const int d1[4] = {dv1.x, dv1.y, dv1.z, dv1.w};

    // issue all row-gathers + scale loads up front
    uint2 a00[4], a01[4], b00[4], b01[4];   // batch 0
    uint2 a10[4], a11[4], b10[4], b11[4];   // batch 1
    float sa0[4], sb0[4], sa1[4], sb1[4];
#pragma unroll
    for (int i = 0; i < 4; ++i) {
        const unsigned char* Ar = A8 + (size_t)s0[i] * 128;
        const unsigned char* Br = B8 + (size_t)d0[i] * 128;
        a00[i] = *(const uint2*)(Ar + sub * 8);
        a01[i] = *(const uint2*)(Ar + 64 + sub * 8);
        b00[i] = *(const uint2*)(Br + sub * 8);
        b01[i] = *(const uint2*)(Br + 64 + sub * 8);
        sa0[i] = sA[s0[i]];
        sb0[i] = sB[d0[i]];
    }
#pragma unroll
    for (int i = 0; i < 4; ++i) {
        const unsigned char* Ar = A8 + (size_t)s1[i] * 128;
        const unsigned char* Br = B8 + (size_t)d1[i] * 128;
        a10[i] = *(const uint2*)(Ar + sub * 8);
        a11[i] = *(const uint2*)(Ar + 64 + sub * 8);
        b10[i] = *(const uint2*)(Br + sub * 8);
        b11[i] = *(const uint2*)(Br + 64 + sub * 8);
        sa1[i] = sA[s1[i]];
        sb1[i] = sB[d1[i]];
    }

    const float4 w0 = *(const float4*)(W2 + sub * 8);
    const float4 w1 = *(const float4*)(W2 + sub * 8 + 4);
    const float4 w2 = *(const float4*)(W2 + 64 + sub * 8);
    const float4 w3 = *(const float4*)(W2 + 64 + sub * 8 + 4);
    const float bias = b2[0];

#define BATCH(AV0, AV1, BV0, BV1, SAV, SBV, EBASE)                             \
    _Pragma("unroll")                                                          \
    for (int i = 0; i < 4; ++i) {                                              \
        float sacc = 0.f;                                                      \
        sacc = dot4q(AV0[i].x, BV0[i].x, SAV[i], SBV[i], w0, sacc);            \
        sacc = dot4q(AV0[i].y, BV0[i].y, SAV[i], SBV[i], w1, sacc);            \
        sacc = dot4q(AV1[i].x, BV1[i].x, SAV[i], SBV[i], w2, sacc);            \
        sacc = dot4q(AV1[i].y, BV1[i].y, SAV[i], SBV[i], w3, sacc);            \
        sacc += __shfl_xor(sacc, 1);                                           \
        sacc += __shfl_xor(sacc, 2);                                           \
        sacc += __shfl_xor(sacc, 4);                                           \
        if (sub == 0) out[(EBASE) + i] = sacc + bias;                          \
    }

    BATCH(a00, a01, b00, b01, sa0, sb0, e0)
    BATCH(a10, a11, b10, b11, sa1, sb1, e1)
#undef BATCH
}

extern "C" void kernel_launch(void* const* d_in, const int* in_sizes, int n_in,
                              void* d_out, int out_size, void* d_ws, size_t ws_size,
                              hipStream_t stream) {
    const float* h   = (const float*)d_in[0];
    const int*   src = (const int*)d_in[1];
    const int*   dst = (const int*)d_in[2];
    const float* W1  = (const float*)d_in[3];
    const float* b1  = (const float*)d_in[4];
    const float* W2  = (const float*)d_in[5];
    const float* b2  = (const float*)d_in[6];
    float* out = (float*)d_out;

    // workspace: Wt bf16 [256][128] | A8 u8 [100000][128] | B8 u8 [100000][128]
    //            | sA f32 [100000] | sB f32 [100000]
    unsigned short* Wt = (unsigned short*)d_ws;
    unsigned char*  A8 = (unsigned char*)(Wt + 256 * 128);
    unsigned char*  B8 = A8 + (size_t)N_NODES * 128;
    float*          sA = (float*)(B8 + (size_t)N_NODES * 128);
    float*          sB = sA + N_NODES;

    prep_wt<<<128, 256, 0, stream>>>(W1, Wt);
    node_proj<<<NBLK, 256, 0, stream>>>(h, Wt, b1, A8, B8, sA, sB);
    edge_score<<<EBLK, 256, 0, stream>>>(A8, B8, sA, sB, src, dst, W2, b2, out);
}